// Round 5
// baseline (357.997 us; speedup 1.0000x reference)
//
#include <hip/hip_runtime.h>
#include <hip/hip_bf16.h>

#define SEQ   2048
#define NH    12
#define MTOK  8192   // 4*2048 token rows

typedef __attribute__((ext_vector_type(8))) short short8;
typedef __attribute__((ext_vector_type(4))) short short4v;
typedef __attribute__((ext_vector_type(4))) float f32x4;

__device__ inline short f2bf(float x) {
  __hip_bfloat16 h = __float2bfloat16(x);
  return *(short*)&h;
}
// RNE bf16 pack for known-finite values (3 VALU ops, no NaN branch)
__device__ inline short f2bf_fast(float x) {
  unsigned u = __float_as_uint(x);
  return (short)((u + 0x7FFF + ((u >> 16) & 1)) >> 16);
}

#define GLL(gp, lp) __builtin_amdgcn_global_load_lds( \
    (const __attribute__((address_space(1))) void*)(gp), \
    (__attribute__((address_space(3))) void*)(lp), 16, 0, 0)

#define MFMA(a, b, c) __builtin_amdgcn_mfma_f32_16x16x32_bf16(a, b, c, 0, 0, 0)

// log2(e)*0.125 : folded into Q so p = exp2(S + maskbias)
#define QSCALE 0.18033688011112042f
#define MBSCALE -14426.950408889634f  // -10000*log2(e)

// ---------------------------------------------------------------------------
__global__ __launch_bounds__(256) void to_bf16(
    const float* __restrict__ in, short* __restrict__ out, int n4) {
  int i = blockIdx.x * 256 + threadIdx.x;
  if (i >= n4) return;
  float4 v = ((const float4*)in)[i];
  short4v o;
  o[0] = f2bf(v.x); o[1] = f2bf(v.y); o[2] = f2bf(v.z); o[3] = f2bf(v.w);
  ((short4v*)out)[i] = o;
}

// fused Wq|Wk|Wv -> bf16 [2304][768]
__global__ __launch_bounds__(256) void conv_wqkv(
    const float* __restrict__ Wq, const float* __restrict__ Wk,
    const float* __restrict__ Wv, short* __restrict__ out) {
  int idx = blockIdx.x * 256 + threadIdx.x;  // 2304*192
  int r = idx / 192, c = (idx - r * 192) * 4;
  const float* src = r < 768 ? &Wq[(size_t)r * 768]
                   : r < 1536 ? &Wk[(size_t)(r - 768) * 768]
                              : &Wv[(size_t)(r - 1536) * 768];
  float4 v = *(const float4*)&src[c];
  short4v o;
  o[0] = f2bf(v.x); o[1] = f2bf(v.y); o[2] = f2bf(v.z); o[3] = f2bf(v.w);
  *(short4v*)&out[(size_t)r * 768 + c] = o;
}

__global__ __launch_bounds__(256) void maskbias(
    const float* __restrict__ mask, float* __restrict__ mb) {
  int i = blockIdx.x * 256 + threadIdx.x;
  if (i < MTOK) mb[i] = (1.f - mask[i]) * MBSCALE;
}

// ---------------------------------------------------------------------------
// QKV GEMM: writes Qb (pre-scaled by QSCALE), Kb, Vt (transposed [b,h,d,s]).
// ---------------------------------------------------------------------------
__global__ __launch_bounds__(256) void gemm_qkv(
    const short* __restrict__ A, const short* __restrict__ B,
    const float* __restrict__ bq, const float* __restrict__ bk,
    const float* __restrict__ bv, short* __restrict__ Qb,
    short* __restrict__ Kb, short* __restrict__ Vt) {
  __shared__ __align__(16) short As[128 * 32];
  __shared__ __align__(16) short Bs[128 * 32];
  const int t = threadIdx.x;
  const int wid = t >> 6, lane = t & 63, l15 = lane & 15, quad = lane >> 4;
  const int bm = blockIdx.x * 128, bn = blockIdx.y * 128;
  const int mq = (wid & 1) * 64, nq = (wid >> 1) * 64;
  const int srow = lane >> 2, scol = (lane & 3) * 8;

  f32x4 acc[4][4] = {};
  const short* gA0 = A + (size_t)(bm + wid * 16 + srow) * 768 + scol;
  const short* gA1 = A + (size_t)(bm + 64 + wid * 16 + srow) * 768 + scol;
  const short* gB0 = B + (size_t)(bn + wid * 16 + srow) * 768 + scol;
  const short* gB1 = B + (size_t)(bn + 64 + wid * 16 + srow) * 768 + scol;

  for (int k0 = 0; k0 < 768; k0 += 32) {
    GLL(gA0 + k0, &As[(wid * 16) * 32]);
    GLL(gA1 + k0, &As[(64 + wid * 16) * 32]);
    GLL(gB0 + k0, &Bs[(wid * 16) * 32]);
    GLL(gB1 + k0, &Bs[(64 + wid * 16) * 32]);
    __syncthreads();
    short8 a[4], b[4];
#pragma unroll
    for (int mt = 0; mt < 4; ++mt)
      a[mt] = *(const short8*)&As[(mq + mt * 16 + l15) * 32 + quad * 8];
#pragma unroll
    for (int nt = 0; nt < 4; ++nt)
      b[nt] = *(const short8*)&Bs[(nq + nt * 16 + l15) * 32 + quad * 8];
#pragma unroll
    for (int mt = 0; mt < 4; ++mt)
#pragma unroll
      for (int nt = 0; nt < 4; ++nt)
        acc[mt][nt] = MFMA(a[mt], b[nt], acc[mt][nt]);
    __syncthreads();
  }

  const int seg = bn >= 1536 ? 2 : (bn >= 768 ? 1 : 0);
  const float* bias = seg == 0 ? bq : (seg == 1 ? bk : bv);
  const int colbase = bn - seg * 768;

  if (seg < 2) {
    short* dst = seg == 0 ? Qb : Kb;
    const float sc = seg == 0 ? QSCALE : 1.f;
#pragma unroll
    for (int mt = 0; mt < 4; ++mt)
#pragma unroll
      for (int nt = 0; nt < 4; ++nt) {
        int col = colbase + nq + nt * 16 + l15;
        float bias_v = bias[col];
#pragma unroll
        for (int i = 0; i < 4; ++i) {
          int row = bm + mq + mt * 16 + quad * 4 + i;
          dst[(size_t)row * 768 + col] = f2bf((acc[mt][nt][i] + bias_v) * sc);
        }
      }
  } else {
#pragma unroll
    for (int mt = 0; mt < 4; ++mt) {
      int row0 = bm + mq + mt * 16 + quad * 4;
      int b_ = row0 >> 11, s = row0 & 2047;
#pragma unroll
      for (int nt = 0; nt < 4; ++nt) {
        int col = colbase + nq + nt * 16 + l15;
        float bias_v = bias[col];
        int h = col >> 6, d = col & 63;
        short4v pv;
#pragma unroll
        for (int i = 0; i < 4; ++i) pv[i] = f2bf(acc[mt][nt][i] + bias_v);
        *(short4v*)&Vt[(((size_t)b_ * NH + h) * 64 + d) * 2048 + s] = pv;
      }
    }
  }
}

// ---------------------------------------------------------------------------
// Barrier-free MFMA flash attention v5.
// Grid (48 bh, 16 qtile): all q-blocks of a bh share an XCD (id%8 = bh%8),
// 6 bh/XCD -> K+V slice (3 MB) L2-resident.
// K frags single-buffer-rotated (next tile loaded right after S-MFMAs),
// V frags issued before exp phase; p = exp2(S + maskbias) (scale pre-folded
// into Q); manual RNE bf16 pack; l via ones-MFMA; P round-trip in LDS.
// ---------------------------------------------------------------------------
__global__ __launch_bounds__(256) void attn_v5(
    const short* __restrict__ Qb, const short* __restrict__ Kb,
    const short* __restrict__ Vt, const float* __restrict__ maskb,
    short* __restrict__ Ctx) {
  __shared__ __align__(16) short P[4 * 32 * 72];
  const int t = threadIdx.x;
  const int w = t >> 6, lane = t & 63, l15 = lane & 15, quad = lane >> 4;
  const int bh = blockIdx.x, b = bh / NH, h = bh % NH;
  const int q0 = blockIdx.y * 128;

  short8 qa[2][2];
#pragma unroll
  for (int mt = 0; mt < 2; ++mt)
#pragma unroll
    for (int ks = 0; ks < 2; ++ks) {
      int row = b * 2048 + q0 + w * 32 + mt * 16 + l15;
      qa[mt][ks] = *(const short8*)&Qb[(size_t)row * 768 + h * 64 + ks * 32 + quad * 8];
    }

  f32x4 O[2][4] = {};
  f32x4 lacc[2] = {};
  short8 ones;
#pragma unroll
  for (int j = 0; j < 8; ++j) ones[j] = (short)0x3F80;  // bf16 1.0

  const short* Kp = Kb + (size_t)b * 2048 * 768 + h * 64;
  const short* Vbase = Vt + ((size_t)b * NH + h) * 64 * 2048;
  const float* mb = maskb + b * 2048;
  short* Pw = &P[w * 2304];

  // prologue: tile-0 K fragments
  short8 kb[2][4];
#pragma unroll
  for (int ks = 0; ks < 2; ++ks)
#pragma unroll
    for (int nt = 0; nt < 4; ++nt)
      kb[ks][nt] = *(const short8*)&Kp[(size_t)(nt * 16 + l15) * 768 +
                                       ks * 32 + quad * 8];

  for (int k0 = 0; k0 < SEQ; k0 += 64) {
    // S = Q.K^T (kb resident)
    f32x4 S[2][4] = {};
#pragma unroll
    for (int ks = 0; ks < 2; ++ks)
#pragma unroll
      for (int nt = 0; nt < 4; ++nt) {
        S[0][nt] = MFMA(qa[0][ks], kb[ks][nt], S[0][nt]);
        S[1][nt] = MFMA(qa[1][ks], kb[ks][nt], S[1][nt]);
      }
    // rotate in next tile's K (latency covered by exp+PV below)
    const int kn = (k0 + 64) & 2047;
#pragma unroll
    for (int ks = 0; ks < 2; ++ks)
#pragma unroll
      for (int nt = 0; nt < 4; ++nt)
        kb[ks][nt] = *(const short8*)&Kp[(size_t)(kn + nt * 16 + l15) * 768 +
                                         ks * 32 + quad * 8];
    // this tile's V (latency covered by exp phase)
    short8 vb[2][4];
#pragma unroll
    for (int ks = 0; ks < 2; ++ks)
#pragma unroll
      for (int nt = 0; nt < 4; ++nt)
        vb[ks][nt] = *(const short8*)&Vbase[(size_t)(nt * 16 + l15) * 2048 +
                                            k0 + ks * 32 + quad * 8];
    float bs[4];
#pragma unroll
    for (int nt = 0; nt < 4; ++nt) bs[nt] = mb[k0 + nt * 16 + l15];

    // p = exp2(S + bias) -> bf16 P in LDS (C-layout -> A-layout)
#pragma unroll
    for (int mt = 0; mt < 2; ++mt)
#pragma unroll
      for (int nt = 0; nt < 4; ++nt)
#pragma unroll
        for (int i = 0; i < 4; ++i) {
          float p = exp2f(S[mt][nt][i] + bs[nt]);
          Pw[(mt * 16 + quad * 4 + i) * 72 + nt * 16 + l15] = f2bf_fast(p);
        }

    // O += P.V ; l += P.1  (P wave-local: no barriers)
#pragma unroll
    for (int ks = 0; ks < 2; ++ks) {
      short8 pa0 = *(const short8*)&Pw[(l15) * 72 + ks * 32 + quad * 8];
      short8 pa1 = *(const short8*)&Pw[(16 + l15) * 72 + ks * 32 + quad * 8];
#pragma unroll
      for (int nt = 0; nt < 4; ++nt) {
        O[0][nt] = MFMA(pa0, vb[ks][nt], O[0][nt]);
        O[1][nt] = MFMA(pa1, vb[ks][nt], O[1][nt]);
      }
      lacc[0] = MFMA(pa0, ones, lacc[0]);
      lacc[1] = MFMA(pa1, ones, lacc[1]);
    }
  }

#pragma unroll
  for (int mt = 0; mt < 2; ++mt)
#pragma unroll
    for (int i = 0; i < 4; ++i) {
      float inv = 1.f / lacc[mt][i];
      int row = b * 2048 + q0 + w * 32 + mt * 16 + quad * 4 + i;
#pragma unroll
      for (int nt = 0; nt < 4; ++nt)
        Ctx[(size_t)row * 768 + h * 64 + nt * 16 + l15] =
            f2bf_fast(O[mt][nt][i] * inv);
    }
}

// ---------------------------------------------------------------------------
__global__ __launch_bounds__(256) void gemm_out(
    const short* __restrict__ A, const short* __restrict__ B,
    const float* __restrict__ bias, float* __restrict__ C) {
  __shared__ __align__(16) short As[128 * 32];
  __shared__ __align__(16) short Bs[128 * 32];
  const int t = threadIdx.x;
  const int wid = t >> 6, lane = t & 63, l15 = lane & 15, quad = lane >> 4;
  const int bm = blockIdx.x * 128, bn = blockIdx.y * 128;
  const int mq = (wid & 1) * 64, nq = (wid >> 1) * 64;
  const int srow = lane >> 2, scol = (lane & 3) * 8;

  f32x4 acc[4][4] = {};
  const short* gA0 = A + (size_t)(bm + wid * 16 + srow) * 768 + scol;
  const short* gA1 = A + (size_t)(bm + 64 + wid * 16 + srow) * 768 + scol;
  const short* gB0 = B + (size_t)(bn + wid * 16 + srow) * 768 + scol;
  const short* gB1 = B + (size_t)(bn + 64 + wid * 16 + srow) * 768 + scol;

  for (int k0 = 0; k0 < 768; k0 += 32) {
    GLL(gA0 + k0, &As[(wid * 16) * 32]);
    GLL(gA1 + k0, &As[(64 + wid * 16) * 32]);
    GLL(gB0 + k0, &Bs[(wid * 16) * 32]);
    GLL(gB1 + k0, &Bs[(64 + wid * 16) * 32]);
    __syncthreads();
    short8 a[4], b[4];
#pragma unroll
    for (int mt = 0; mt < 4; ++mt)
      a[mt] = *(const short8*)&As[(mq + mt * 16 + l15) * 32 + quad * 8];
#pragma unroll
    for (int nt = 0; nt < 4; ++nt)
      b[nt] = *(const short8*)&Bs[(nq + nt * 16 + l15) * 32 + quad * 8];
#pragma unroll
    for (int mt = 0; mt < 4; ++mt)
#pragma unroll
      for (int nt = 0; nt < 4; ++nt)
        acc[mt][nt] = MFMA(a[mt], b[nt], acc[mt][nt]);
    __syncthreads();
  }

#pragma unroll
  for (int mt = 0; mt < 4; ++mt)
#pragma unroll
    for (int nt = 0; nt < 4; ++nt) {
      int col = bn + nq + nt * 16 + l15;
      float bias_v = bias[col];
#pragma unroll
      for (int i = 0; i < 4; ++i) {
        int row = bm + mq + mt * 16 + quad * 4 + i;
        C[(size_t)row * 768 + col] = acc[mt][nt][i] + bias_v;
      }
    }
}

// ---------------------------------------------------------------------------
extern "C" void kernel_launch(void* const* d_in, const int* in_sizes, int n_in,
                              void* d_out, int out_size, void* d_ws,
                              size_t ws_size, hipStream_t stream) {
  const float* hs   = (const float*)d_in[0];
  const float* mask = (const float*)d_in[1];
  const float* Wq   = (const float*)d_in[2];
  const float* bq   = (const float*)d_in[3];
  const float* Wk   = (const float*)d_in[4];
  const float* bk   = (const float*)d_in[5];
  const float* Wv   = (const float*)d_in[6];
  const float* bv   = (const float*)d_in[7];
  const float* Wo   = (const float*)d_in[8];
  const float* bo   = (const float*)d_in[9];

  char* ws = (char*)d_ws;
  short* Xb    = (short*)(ws);               // 8192x768  bf16  12.58MB
  short* Wqkvb = (short*)(ws + 12582912);    // 2304x768  bf16   3.54MB
  short* Wob   = (short*)(ws + 16121856);    // 768x768   bf16   1.18MB
  short* Qb    = (short*)(ws + 17301504);    // 8192x768  bf16  12.58MB
  short* Kb    = (short*)(ws + 29884416);    // 8192x768  bf16  12.58MB
  short* Vtg   = (short*)(ws + 42467328);    // [4][12][64][2048] 12.58MB
  short* Ctxb  = (short*)(ws + 55050240);    // 8192x768  bf16  12.58MB
  float* mbias = (float*)(ws + 67633152);    // 8192 f32  32KB

  to_bf16<<<6144, 256, 0, stream>>>(hs, Xb, 1572864);
  conv_wqkv<<<1728, 256, 0, stream>>>(Wq, Wk, Wv, Wqkvb);
  to_bf16<<<576, 256, 0, stream>>>(Wo, Wob, 147456);
  maskbias<<<32, 256, 0, stream>>>(mask, mbias);

  gemm_qkv<<<dim3(64, 18), 256, 0, stream>>>(Xb, Wqkvb, bq, bk, bv,
                                             Qb, Kb, Vtg);
  attn_v5<<<dim3(48, 16), 256, 0, stream>>>(Qb, Kb, Vtg, mbias, Ctxb);
  gemm_out<<<dim3(64, 6), 256, 0, stream>>>(Ctxb, Wob, bo, (float*)d_out);
}

// Round 6
// 288.701 us; speedup vs baseline: 1.2400x; 1.2400x over previous
//
#include <hip/hip_runtime.h>
#include <hip/hip_bf16.h>

#define SEQ   2048
#define NH    12
#define MTOK  8192   // 4*2048 token rows

typedef __attribute__((ext_vector_type(8))) short short8;
typedef __attribute__((ext_vector_type(4))) short short4v;
typedef __attribute__((ext_vector_type(4))) float f32x4;

__device__ inline short f2bf(float x) {
  __hip_bfloat16 h = __float2bfloat16(x);
  return *(short*)&h;
}

#define GLL(gp, lp) __builtin_amdgcn_global_load_lds( \
    (const __attribute__((address_space(1))) void*)(gp), \
    (__attribute__((address_space(3))) void*)(lp), 16, 0, 0)

#define MFMA(a, b, c) __builtin_amdgcn_mfma_f32_16x16x32_bf16(a, b, c, 0, 0, 0)

// log2(e)*0.125 folded into Q so p = exp2(S + maskbias)
#define QSCALE 0.18033688011112042f
#define MBSCALE -14426.950408889634f  // -10000*log2(e)

// ---------------------------------------------------------------------------
__global__ __launch_bounds__(256) void to_bf16(
    const float* __restrict__ in, short* __restrict__ out, int n4) {
  int i = blockIdx.x * 256 + threadIdx.x;
  if (i >= n4) return;
  float4 v = ((const float4*)in)[i];
  short4v o;
  o[0] = f2bf(v.x); o[1] = f2bf(v.y); o[2] = f2bf(v.z); o[3] = f2bf(v.w);
  ((short4v*)out)[i] = o;
}

__global__ __launch_bounds__(256) void conv_wqkv(
    const float* __restrict__ Wq, const float* __restrict__ Wk,
    const float* __restrict__ Wv, short* __restrict__ out) {
  int idx = blockIdx.x * 256 + threadIdx.x;  // 2304*192
  int r = idx / 192, c = (idx - r * 192) * 4;
  const float* src = r < 768 ? &Wq[(size_t)r * 768]
                   : r < 1536 ? &Wk[(size_t)(r - 768) * 768]
                              : &Wv[(size_t)(r - 1536) * 768];
  float4 v = *(const float4*)&src[c];
  short4v o;
  o[0] = f2bf(v.x); o[1] = f2bf(v.y); o[2] = f2bf(v.z); o[3] = f2bf(v.w);
  *(short4v*)&out[(size_t)r * 768 + c] = o;
}

__global__ __launch_bounds__(256) void maskbias(
    const float* __restrict__ mask, float* __restrict__ mb) {
  int i = blockIdx.x * 256 + threadIdx.x;
  if (i < MTOK) mb[i] = (1.f - mask[i]) * MBSCALE;
}

// ---------------------------------------------------------------------------
// QKV GEMM (m97 pattern): writes Qb (pre-scaled QSCALE), Kb, Vt [b,h,d,s].
// ---------------------------------------------------------------------------
__global__ __launch_bounds__(256) void gemm_qkv(
    const short* __restrict__ A, const short* __restrict__ B,
    const float* __restrict__ bq, const float* __restrict__ bk,
    const float* __restrict__ bv, short* __restrict__ Qb,
    short* __restrict__ Kb, short* __restrict__ Vt) {
  __shared__ __align__(16) short As[128 * 32];
  __shared__ __align__(16) short Bs[128 * 32];
  const int t = threadIdx.x;
  const int wid = t >> 6, lane = t & 63, l15 = lane & 15, quad = lane >> 4;
  const int bm = blockIdx.x * 128, bn = blockIdx.y * 128;
  const int mq = (wid & 1) * 64, nq = (wid >> 1) * 64;
  const int srow = lane >> 2, scol = (lane & 3) * 8;

  f32x4 acc[4][4] = {};
  const short* gA0 = A + (size_t)(bm + wid * 16 + srow) * 768 + scol;
  const short* gA1 = A + (size_t)(bm + 64 + wid * 16 + srow) * 768 + scol;
  const short* gB0 = B + (size_t)(bn + wid * 16 + srow) * 768 + scol;
  const short* gB1 = B + (size_t)(bn + 64 + wid * 16 + srow) * 768 + scol;

  for (int k0 = 0; k0 < 768; k0 += 32) {
    GLL(gA0 + k0, &As[(wid * 16) * 32]);
    GLL(gA1 + k0, &As[(64 + wid * 16) * 32]);
    GLL(gB0 + k0, &Bs[(wid * 16) * 32]);
    GLL(gB1 + k0, &Bs[(64 + wid * 16) * 32]);
    __syncthreads();
    short8 a[4], b[4];
#pragma unroll
    for (int mt = 0; mt < 4; ++mt)
      a[mt] = *(const short8*)&As[(mq + mt * 16 + l15) * 32 + quad * 8];
#pragma unroll
    for (int nt = 0; nt < 4; ++nt)
      b[nt] = *(const short8*)&Bs[(nq + nt * 16 + l15) * 32 + quad * 8];
#pragma unroll
    for (int mt = 0; mt < 4; ++mt)
#pragma unroll
      for (int nt = 0; nt < 4; ++nt)
        acc[mt][nt] = MFMA(a[mt], b[nt], acc[mt][nt]);
    __syncthreads();
  }

  const int seg = bn >= 1536 ? 2 : (bn >= 768 ? 1 : 0);
  const float* bias = seg == 0 ? bq : (seg == 1 ? bk : bv);
  const int colbase = bn - seg * 768;

  if (seg < 2) {
    short* dst = seg == 0 ? Qb : Kb;
    const float sc = seg == 0 ? QSCALE : 1.f;
#pragma unroll
    for (int mt = 0; mt < 4; ++mt)
#pragma unroll
      for (int nt = 0; nt < 4; ++nt) {
        int col = colbase + nq + nt * 16 + l15;
        float bias_v = bias[col];
#pragma unroll
        for (int i = 0; i < 4; ++i) {
          int row = bm + mq + mt * 16 + quad * 4 + i;
          dst[(size_t)row * 768 + col] = f2bf((acc[mt][nt][i] + bias_v) * sc);
        }
      }
  } else {
#pragma unroll
    for (int mt = 0; mt < 4; ++mt) {
      int row0 = bm + mq + mt * 16 + quad * 4;
      int b_ = row0 >> 11, s = row0 & 2047;
#pragma unroll
      for (int nt = 0; nt < 4; ++nt) {
        int col = colbase + nq + nt * 16 + l15;
        float bias_v = bias[col];
        int h = col >> 6, d = col & 63;
        short4v pv;
#pragma unroll
        for (int i = 0; i < 4; ++i) pv[i] = f2bf(acc[mt][nt][i] + bias_v);
        *(short4v*)&Vt[(((size_t)b_ * NH + h) * 64 + d) * 2048 + s] = pv;
      }
    }
  }
}

// ---------------------------------------------------------------------------
// attn_v6: LDS-staged flash attention.
// Grid (48 bh, 16 qtile) -> XCD-local K/V (FETCH ~compulsory, proven r5).
// K/V tiles staged via global_load_lds with XOR chunk swizzle
// (physical 16B chunk = logical ^ (row&7)) -> 2-way (free) LDS reads
// without padding (GLL forbids pads: dest = base + lane*16).
// Q frags in registers; P round-trip wave-private LDS (no barrier);
// p = exp2(S + maskbias); l via ones-MFMA; 2 barriers/tile (m97 shape).
// ---------------------------------------------------------------------------
__global__ __launch_bounds__(256) void attn_v6(
    const short* __restrict__ Qb, const short* __restrict__ Kb,
    const short* __restrict__ Vt, const float* __restrict__ maskb,
    short* __restrict__ Ctx) {
  __shared__ __align__(16) short Ks[64 * 64];   // [key][dchunk^swz]
  __shared__ __align__(16) short Vs[64 * 64];   // [d][keychunk^swz]
  __shared__ __align__(16) short P[4 * 32 * 72];
  const int t = threadIdx.x;
  const int w = t >> 6, lane = t & 63, l15 = lane & 15, quad = lane >> 4;
  const int bh = blockIdx.x, b = bh / NH, h = bh % NH;
  const int q0 = blockIdx.y * 128;

  // Q fragments (rows pre-scaled by QSCALE in gemm_qkv)
  short8 qa[2][2];
#pragma unroll
  for (int mt = 0; mt < 2; ++mt)
#pragma unroll
    for (int ks = 0; ks < 2; ++ks) {
      int row = b * 2048 + q0 + w * 32 + mt * 16 + l15;
      qa[mt][ks] = *(const short8*)&Qb[(size_t)row * 768 + h * 64 + ks * 32 + quad * 8];
    }

  f32x4 O[2][4] = {};
  f32x4 lacc[2] = {};
  short8 ones;
#pragma unroll
  for (int j = 0; j < 8; ++j) ones[j] = (short)0x3F80;  // bf16 1.0

  // staging sources: wave w covers rows [w*16, w*16+16) in 2 GLL issues
  const int r0 = w * 16 + (lane >> 3);    // rows r0 and r0+8
  const int pc = lane & 7;                 // physical 16B chunk within row
  const int swz0 = (pc ^ (r0 & 7)) * 8;
  const int swz1 = (pc ^ ((r0 + 8) & 7)) * 8;
  const short* gK0 = Kb + (size_t)(b * 2048 + r0) * 768 + h * 64 + swz0;
  const short* gK1 = Kb + (size_t)(b * 2048 + r0 + 8) * 768 + h * 64 + swz1;
  const short* gV0 = Vt + ((size_t)bh * 64 + r0) * 2048 + swz0;
  const short* gV1 = Vt + ((size_t)bh * 64 + r0 + 8) * 2048 + swz1;
  const float* mb = maskb + b * 2048;
  short* Pw = &P[w * 2304];
  const int rswz = (l15 & 7);  // read-side swizzle key (row term)

  for (int k0 = 0; k0 < SEQ; k0 += 64) {
    GLL(gK0 + (size_t)k0 * 768, &Ks[(w * 16) * 64]);
    GLL(gK1 + (size_t)k0 * 768, &Ks[(w * 16 + 8) * 64]);
    GLL(gV0 + k0, &Vs[(w * 16) * 64]);
    GLL(gV1 + k0, &Vs[(w * 16 + 8) * 64]);
    __syncthreads();

    // S = Q.K^T from LDS (swizzled chunks)
    f32x4 S[2][4] = {};
#pragma unroll
    for (int ks = 0; ks < 2; ++ks) {
      short8 kb[4];
#pragma unroll
      for (int nt = 0; nt < 4; ++nt)
        kb[nt] = *(const short8*)&Ks[(nt * 16 + l15) * 64 +
                                     (((ks * 4 + quad) ^ rswz) * 8)];
#pragma unroll
      for (int nt = 0; nt < 4; ++nt) {
        S[0][nt] = MFMA(qa[0][ks], kb[nt], S[0][nt]);
        S[1][nt] = MFMA(qa[1][ks], kb[nt], S[1][nt]);
      }
    }

    float bs[4];
#pragma unroll
    for (int nt = 0; nt < 4; ++nt) bs[nt] = mb[k0 + nt * 16 + l15];

    // p = exp2(S + bias) -> bf16 P (C-layout -> A-layout via wave-private LDS)
#pragma unroll
    for (int mt = 0; mt < 2; ++mt)
#pragma unroll
      for (int nt = 0; nt < 4; ++nt)
#pragma unroll
        for (int i = 0; i < 4; ++i) {
          float p = exp2f(S[mt][nt][i] + bs[nt]);
          Pw[(mt * 16 + quad * 4 + i) * 72 + nt * 16 + l15] = f2bf(p);
        }

    // O += P.V ; l += P.1
#pragma unroll
    for (int ks = 0; ks < 2; ++ks) {
      short8 pa0 = *(const short8*)&Pw[(l15) * 72 + ks * 32 + quad * 8];
      short8 pa1 = *(const short8*)&Pw[(16 + l15) * 72 + ks * 32 + quad * 8];
      short8 vb[4];
#pragma unroll
      for (int nt = 0; nt < 4; ++nt)
        vb[nt] = *(const short8*)&Vs[(nt * 16 + l15) * 64 +
                                     (((ks * 4 + quad) ^ rswz) * 8)];
#pragma unroll
      for (int nt = 0; nt < 4; ++nt) {
        O[0][nt] = MFMA(pa0, vb[nt], O[0][nt]);
        O[1][nt] = MFMA(pa1, vb[nt], O[1][nt]);
      }
      lacc[0] = MFMA(pa0, ones, lacc[0]);
      lacc[1] = MFMA(pa1, ones, lacc[1]);
    }
    __syncthreads();  // all waves done reading Ks/Vs before next GLL
  }

#pragma unroll
  for (int mt = 0; mt < 2; ++mt)
#pragma unroll
    for (int i = 0; i < 4; ++i) {
      float inv = 1.f / lacc[mt][i];
      int row = b * 2048 + q0 + w * 32 + mt * 16 + quad * 4 + i;
#pragma unroll
      for (int nt = 0; nt < 4; ++nt)
        Ctx[(size_t)row * 768 + h * 64 + nt * 16 + l15] =
            f2bf(O[mt][nt][i] * inv);
    }
}

// ---------------------------------------------------------------------------
__global__ __launch_bounds__(256) void gemm_out(
    const short* __restrict__ A, const short* __restrict__ B,
    const float* __restrict__ bias, float* __restrict__ C) {
  __shared__ __align__(16) short As[128 * 32];
  __shared__ __align__(16) short Bs[128 * 32];
  const int t = threadIdx.x;
  const int wid = t >> 6, lane = t & 63, l15 = lane & 15, quad = lane >> 4;
  const int bm = blockIdx.x * 128, bn = blockIdx.y * 128;
  const int mq = (wid & 1) * 64, nq = (wid >> 1) * 64;
  const int srow = lane >> 2, scol = (lane & 3) * 8;

  f32x4 acc[4][4] = {};
  const short* gA0 = A + (size_t)(bm + wid * 16 + srow) * 768 + scol;
  const short* gA1 = A + (size_t)(bm + 64 + wid * 16 + srow) * 768 + scol;
  const short* gB0 = B + (size_t)(bn + wid * 16 + srow) * 768 + scol;
  const short* gB1 = B + (size_t)(bn + 64 + wid * 16 + srow) * 768 + scol;

  for (int k0 = 0; k0 < 768; k0 += 32) {
    GLL(gA0 + k0, &As[(wid * 16) * 32]);
    GLL(gA1 + k0, &As[(64 + wid * 16) * 32]);
    GLL(gB0 + k0, &Bs[(wid * 16) * 32]);
    GLL(gB1 + k0, &Bs[(64 + wid * 16) * 32]);
    __syncthreads();
    short8 a[4], b[4];
#pragma unroll
    for (int mt = 0; mt < 4; ++mt)
      a[mt] = *(const short8*)&As[(mq + mt * 16 + l15) * 32 + quad * 8];
#pragma unroll
    for (int nt = 0; nt < 4; ++nt)
      b[nt] = *(const short8*)&Bs[(nq + nt * 16 + l15) * 32 + quad * 8];
#pragma unroll
    for (int mt = 0; mt < 4; ++mt)
#pragma unroll
      for (int nt = 0; nt < 4; ++nt)
        acc[mt][nt] = MFMA(a[mt], b[nt], acc[mt][nt]);
    __syncthreads();
  }

#pragma unroll
  for (int mt = 0; mt < 4; ++mt)
#pragma unroll
    for (int nt = 0; nt < 4; ++nt) {
      int col = bn + nq + nt * 16 + l15;
      float bias_v = bias[col];
#pragma unroll
      for (int i = 0; i < 4; ++i) {
        int row = bm + mq + mt * 16 + quad * 4 + i;
        C[(size_t)row * 768 + col] = acc[mt][nt][i] + bias_v;
      }
    }
}

// ---------------------------------------------------------------------------
extern "C" void kernel_launch(void* const* d_in, const int* in_sizes, int n_in,
                              void* d_out, int out_size, void* d_ws,
                              size_t ws_size, hipStream_t stream) {
  const float* hs   = (const float*)d_in[0];
  const float* mask = (const float*)d_in[1];
  const float* Wq   = (const float*)d_in[2];
  const float* bq   = (const float*)d_in[3];
  const float* Wk   = (const float*)d_in[4];
  const float* bk   = (const float*)d_in[5];
  const float* Wv   = (const float*)d_in[6];
  const float* bv   = (const float*)d_in[7];
  const float* Wo   = (const float*)d_in[8];
  const float* bo   = (const float*)d_in[9];

  char* ws = (char*)d_ws;
  short* Xb    = (short*)(ws);               // 8192x768  bf16  12.58MB
  short* Wqkvb = (short*)(ws + 12582912);    // 2304x768  bf16   3.54MB
  short* Wob   = (short*)(ws + 16121856);    // 768x768   bf16   1.18MB
  short* Qb    = (short*)(ws + 17301504);    // 8192x768  bf16  12.58MB
  short* Kb    = (short*)(ws + 29884416);    // 8192x768  bf16  12.58MB
  short* Vtg   = (short*)(ws + 42467328);    // [4][12][64][2048] 12.58MB
  short* Ctxb  = (short*)(ws + 55050240);    // 8192x768  bf16  12.58MB
  float* mbias = (float*)(ws + 67633152);    // 8192 f32  32KB

  to_bf16<<<6144, 256, 0, stream>>>(hs, Xb, 1572864);
  conv_wqkv<<<1728, 256, 0, stream>>>(Wq, Wk, Wv, Wqkvb);
  to_bf16<<<576, 256, 0, stream>>>(Wo, Wob, 147456);
  maskbias<<<32, 256, 0, stream>>>(mask, mbias);

  gemm_qkv<<<dim3(64, 18), 256, 0, stream>>>(Xb, Wqkvb, bq, bk, bv,
                                             Qb, Kb, Vtg);
  attn_v6<<<dim3(48, 16), 256, 0, stream>>>(Qb, Kb, Vtg, mbias, Ctxb);
  gemm_out<<<dim3(64, 6), 256, 0, stream>>>(Ctxb, Wob, bo, (float*)d_out);
}

// Round 9
// 237.434 us; speedup vs baseline: 1.5078x; 1.2159x over previous
//
#include <hip/hip_runtime.h>
#include <hip/hip_bf16.h>

#define SEQ   2048
#define NH    12
#define MTOK  8192   // 4*2048 token rows

typedef __attribute__((ext_vector_type(8))) short short8;
typedef __attribute__((ext_vector_type(4))) short short4v;
typedef __attribute__((ext_vector_type(4))) float f32x4;

__device__ inline short f2bf(float x) {
  __hip_bfloat16 h = __float2bfloat16(x);
  return *(short*)&h;
}

#define GLL(gp, lp) __builtin_amdgcn_global_load_lds( \
    (const __attribute__((address_space(1))) void*)(gp), \
    (__attribute__((address_space(3))) void*)(lp), 16, 0, 0)

#define MFMA(a, b, c) __builtin_amdgcn_mfma_f32_16x16x32_bf16(a, b, c, 0, 0, 0)

// K=16 bf16 MFMA — device-pass hedge; host pass only parses, give it a stub
#if !defined(__HIP_DEVICE_COMPILE__)
#define MFMA16(a, b, c) (c)
#elif __has_builtin(__builtin_amdgcn_mfma_f32_16x16x16bf16_1k)
#define MFMA16(a, b, c) __builtin_amdgcn_mfma_f32_16x16x16bf16_1k(a, b, c, 0, 0, 0)
#elif __has_builtin(__builtin_amdgcn_mfma_f32_16x16x16_bf16)
#define MFMA16(a, b, c) __builtin_amdgcn_mfma_f32_16x16x16_bf16(a, b, c, 0, 0, 0)
#else
#error "no 16x16x16 bf16 mfma builtin on device"
#endif

// native exp2 (1 VALU op) hedge
#if !defined(__HIP_DEVICE_COMPILE__)
#define EXP2(x) (x)
#elif __has_builtin(__builtin_amdgcn_exp2f)
#define EXP2(x) __builtin_amdgcn_exp2f(x)
#else
#define EXP2(x) __expf((x) * 0.6931471805599453f)
#endif

// pack two fp32 -> bf16x2 dword (round-half-away; inputs finite)
__device__ inline unsigned pack2bf(float a, float b) {
  unsigned ua = __float_as_uint(a) + 0x8000u;
  unsigned ub = __float_as_uint(b) + 0x8000u;
#if defined(__HIP_DEVICE_COMPILE__) && __has_builtin(__builtin_amdgcn_perm)
  return __builtin_amdgcn_perm(ub, ua, 0x07060302u);
#else
  return (ub & 0xFFFF0000u) | (ua >> 16);
#endif
}

// build a short4v B-fragment from two packed dwords (named storage, no temp)
union PackFrag {
  unsigned u[2];
  short4v s;
};

// log2(e)*0.125 folded into Q so p = exp2(S + maskbias)
#define QSCALE 0.18033688011112042f
#define MBSCALE -14426.950408889634f  // -10000*log2(e)

// ---------------------------------------------------------------------------
__global__ __launch_bounds__(256) void to_bf16(
    const float* __restrict__ in, short* __restrict__ out, int n4) {
  int i = blockIdx.x * 256 + threadIdx.x;
  if (i >= n4) return;
  float4 v = ((const float4*)in)[i];
  short4v o;
  o[0] = f2bf(v.x); o[1] = f2bf(v.y); o[2] = f2bf(v.z); o[3] = f2bf(v.w);
  ((short4v*)out)[i] = o;
}

__global__ __launch_bounds__(256) void conv_wqkv(
    const float* __restrict__ Wq, const float* __restrict__ Wk,
    const float* __restrict__ Wv, short* __restrict__ out) {
  int idx = blockIdx.x * 256 + threadIdx.x;  // 2304*192
  int r = idx / 192, c = (idx - r * 192) * 4;
  const float* src = r < 768 ? &Wq[(size_t)r * 768]
                   : r < 1536 ? &Wk[(size_t)(r - 768) * 768]
                              : &Wv[(size_t)(r - 1536) * 768];
  float4 v = *(const float4*)&src[c];
  short4v o;
  o[0] = f2bf(v.x); o[1] = f2bf(v.y); o[2] = f2bf(v.z); o[3] = f2bf(v.w);
  *(short4v*)&out[(size_t)r * 768 + c] = o;
}

__global__ __launch_bounds__(256) void maskbias(
    const float* __restrict__ mask, float* __restrict__ mb) {
  int i = blockIdx.x * 256 + threadIdx.x;
  if (i < MTOK) mb[i] = (1.f - mask[i]) * MBSCALE;
}

// ---------------------------------------------------------------------------
// QKV GEMM (m97 pattern): writes Qb (pre-scaled QSCALE), Kb, Vt [b,h,d,s].
// ---------------------------------------------------------------------------
__global__ __launch_bounds__(256) void gemm_qkv(
    const short* __restrict__ A, const short* __restrict__ B,
    const float* __restrict__ bq, const float* __restrict__ bk,
    const float* __restrict__ bv, short* __restrict__ Qb,
    short* __restrict__ Kb, short* __restrict__ Vt) {
  __shared__ __align__(16) short As[128 * 32];
  __shared__ __align__(16) short Bs[128 * 32];
  const int t = threadIdx.x;
  const int wid = t >> 6, lane = t & 63, l15 = lane & 15, quad = lane >> 4;
  const int bm = blockIdx.x * 128, bn = blockIdx.y * 128;
  const int mq = (wid & 1) * 64, nq = (wid >> 1) * 64;
  const int srow = lane >> 2, scol = (lane & 3) * 8;

  f32x4 acc[4][4] = {};
  const short* gA0 = A + (size_t)(bm + wid * 16 + srow) * 768 + scol;
  const short* gA1 = A + (size_t)(bm + 64 + wid * 16 + srow) * 768 + scol;
  const short* gB0 = B + (size_t)(bn + wid * 16 + srow) * 768 + scol;
  const short* gB1 = B + (size_t)(bn + 64 + wid * 16 + srow) * 768 + scol;

  for (int k0 = 0; k0 < 768; k0 += 32) {
    GLL(gA0 + k0, &As[(wid * 16) * 32]);
    GLL(gA1 + k0, &As[(64 + wid * 16) * 32]);
    GLL(gB0 + k0, &Bs[(wid * 16) * 32]);
    GLL(gB1 + k0, &Bs[(64 + wid * 16) * 32]);
    __syncthreads();
    short8 a[4], b[4];
#pragma unroll
    for (int mt = 0; mt < 4; ++mt)
      a[mt] = *(const short8*)&As[(mq + mt * 16 + l15) * 32 + quad * 8];
#pragma unroll
    for (int nt = 0; nt < 4; ++nt)
      b[nt] = *(const short8*)&Bs[(nq + nt * 16 + l15) * 32 + quad * 8];
#pragma unroll
    for (int mt = 0; mt < 4; ++mt)
#pragma unroll
      for (int nt = 0; nt < 4; ++nt)
        acc[mt][nt] = MFMA(a[mt], b[nt], acc[mt][nt]);
    __syncthreads();
  }

  const int seg = bn >= 1536 ? 2 : (bn >= 768 ? 1 : 0);
  const float* bias = seg == 0 ? bq : (seg == 1 ? bk : bv);
  const int colbase = bn - seg * 768;

  if (seg < 2) {
    short* dst = seg == 0 ? Qb : Kb;
    const float sc = seg == 0 ? QSCALE : 1.f;
#pragma unroll
    for (int mt = 0; mt < 4; ++mt)
#pragma unroll
      for (int nt = 0; nt < 4; ++nt) {
        int col = colbase + nq + nt * 16 + l15;
        float bias_v = bias[col];
#pragma unroll
        for (int i = 0; i < 4; ++i) {
          int row = bm + mq + mt * 16 + quad * 4 + i;
          dst[(size_t)row * 768 + col] = f2bf((acc[mt][nt][i] + bias_v) * sc);
        }
      }
  } else {
#pragma unroll
    for (int mt = 0; mt < 4; ++mt) {
      int row0 = bm + mq + mt * 16 + quad * 4;
      int b_ = row0 >> 11, s = row0 & 2047;
#pragma unroll
      for (int nt = 0; nt < 4; ++nt) {
        int col = colbase + nq + nt * 16 + l15;
        float bias_v = bias[col];
        int h = col >> 6, d = col & 63;
        short4v pv;
#pragma unroll
        for (int i = 0; i < 4; ++i) pv[i] = f2bf(acc[mt][nt][i] + bias_v);
        *(short4v*)&Vt[(((size_t)b_ * NH + h) * 64 + d) * 2048 + s] = pv;
      }
    }
  }
}

// ---------------------------------------------------------------------------
// attn_v7: S-transposed register-resident-P flash attention.
// QK^T computed as S^T = K.Q^T (A=K-frag, B=Q-frag). S^T's C-layout
// (col=q=l15, row=key=quad*4+i) IS the B-operand layout of 16x16x16 MFMA
// (n=l15, k=quad*4+j) -> exp'd+packed P feeds PV directly from registers.
// PV: O^T[d][q] += V^T-frag (A, ds_read_b64 from Vs[d][key]) x P (B).
// l via ones-MFMA on P regs -> per-lane l[q], no shuffles, no LDS P.
// LDS: Ks+Vs 16KB only, XOR-chunk swizzle (GLL staging, proven r6).
// ---------------------------------------------------------------------------
__global__ __launch_bounds__(256, 3) void attn_v7(
    const short* __restrict__ Qb, const short* __restrict__ Kb,
    const short* __restrict__ Vt, const float* __restrict__ maskb,
    short* __restrict__ Ctx) {
  __shared__ __align__(16) short Ks[64 * 64];   // [key][dchunk^swz]
  __shared__ __align__(16) short Vs[64 * 64];   // [d][keychunk^swz]
  const int t = threadIdx.x;
  const int w = t >> 6, lane = t & 63, l15 = lane & 15, quad = lane >> 4;
  const int bh = blockIdx.x, b = bh / NH, h = bh % NH;
  const int q0 = blockIdx.y * 128;

  // Q fragments (pre-scaled by QSCALE) — used as the B operand of QK
  short8 qa[2][2];
#pragma unroll
  for (int qt = 0; qt < 2; ++qt)
#pragma unroll
    for (int ks = 0; ks < 2; ++ks) {
      int row = b * 2048 + q0 + w * 32 + qt * 16 + l15;
      qa[qt][ks] = *(const short8*)&Qb[(size_t)row * 768 + h * 64 + ks * 32 + quad * 8];
    }

  f32x4 O[2][4] = {};     // O^T tiles: [qt][dt], D[m=d][n=q]
  f32x4 lacc[2] = {};     // l[q] replicated across rows
  short4v ones4;
#pragma unroll
  for (int j = 0; j < 4; ++j) ones4[j] = (short)0x3F80;  // bf16 1.0

  // GLL staging (identical to r6): wave w stages rows [w*16, w*16+16)
  const int r0 = w * 16 + (lane >> 3);
  const int pc = lane & 7;
  const int swz0 = (pc ^ (r0 & 7)) * 8;
  const int swz1 = (pc ^ ((r0 + 8) & 7)) * 8;
  const short* gK0 = Kb + (size_t)(b * 2048 + r0) * 768 + h * 64 + swz0;
  const short* gK1 = Kb + (size_t)(b * 2048 + r0 + 8) * 768 + h * 64 + swz1;
  const short* gV0 = Vt + ((size_t)bh * 64 + r0) * 2048 + swz0;
  const short* gV1 = Vt + ((size_t)bh * 64 + r0 + 8) * 2048 + swz1;
  const float* mb = maskb + b * 2048;
  const int rs = l15 & 7;  // read-side swizzle key

  for (int k0 = 0; k0 < SEQ; k0 += 64) {
    GLL(gK0 + (size_t)k0 * 768, &Ks[(w * 16) * 64]);
    GLL(gK1 + (size_t)k0 * 768, &Ks[(w * 16 + 8) * 64]);
    GLL(gV0 + k0, &Vs[(w * 16) * 64]);
    GLL(gV1 + k0, &Vs[(w * 16 + 8) * 64]);
    __syncthreads();

    // S^T[kt][qt] = K.Q^T   (rows=key, cols=q)
    f32x4 S[4][2] = {};
#pragma unroll
    for (int ks = 0; ks < 2; ++ks) {
      short8 kb[4];
#pragma unroll
      for (int kt = 0; kt < 4; ++kt)
        kb[kt] = *(const short8*)&Ks[(kt * 16 + l15) * 64 +
                                     (((ks * 4 + quad) ^ rs) * 8)];
#pragma unroll
      for (int kt = 0; kt < 4; ++kt) {
        S[kt][0] = MFMA(kb[kt], qa[0][ks], S[kt][0]);
        S[kt][1] = MFMA(kb[kt], qa[1][ks], S[kt][1]);
      }
    }

    // p = exp2(S^T + maskbias[key]) -> packed bf16 B-fragments (registers!)
    short4v pb[4][2];
#pragma unroll
    for (int kt = 0; kt < 4; ++kt) {
      float4 mb4 = *(const float4*)&mb[k0 + kt * 16 + quad * 4];
#pragma unroll
      for (int qt = 0; qt < 2; ++qt) {
        float p0 = EXP2(S[kt][qt][0] + mb4.x);
        float p1 = EXP2(S[kt][qt][1] + mb4.y);
        float p2 = EXP2(S[kt][qt][2] + mb4.z);
        float p3 = EXP2(S[kt][qt][3] + mb4.w);
        PackFrag pf;
        pf.u[0] = pack2bf(p0, p1);
        pf.u[1] = pack2bf(p2, p3);
        pb[kt][qt] = pf.s;
      }
    }

    // l += P.1 (per-lane l[q] in all rows)
#pragma unroll
    for (int kt = 0; kt < 4; ++kt) {
      lacc[0] = MFMA16(ones4, pb[kt][0], lacc[0]);
      lacc[1] = MFMA16(ones4, pb[kt][1], lacc[1]);
    }

    // O^T += V^T.P^T : A = V^T[d][key-chunk] (ds_read_b64), B = pb
#pragma unroll
    for (int kt = 0; kt < 4; ++kt) {
#pragma unroll
      for (int dt = 0; dt < 4; ++dt) {
        short4v av = *(const short4v*)&Vs[(dt * 16 + l15) * 64 +
            (((kt * 2 + (quad >> 1)) ^ rs) * 8) + (quad & 1) * 4];
        O[0][dt] = MFMA16(av, pb[kt][0], O[0][dt]);
        O[1][dt] = MFMA16(av, pb[kt][1], O[1][dt]);
      }
    }
    __syncthreads();
  }

  // epilogue: lane holds O^T[d=quad*4+i][q=l15]; l[q] = lacc[qt][any]
#pragma unroll
  for (int qt = 0; qt < 2; ++qt) {
    float inv = 1.f / lacc[qt][0];
    int row = b * 2048 + q0 + w * 32 + qt * 16 + l15;
#pragma unroll
    for (int dt = 0; dt < 4; ++dt) {
      PackFrag pf;
      pf.u[0] = pack2bf(O[qt][dt][0] * inv, O[qt][dt][1] * inv);
      pf.u[1] = pack2bf(O[qt][dt][2] * inv, O[qt][dt][3] * inv);
      *(short4v*)&Ctx[(size_t)row * 768 + h * 64 + dt * 16 + quad * 4] = pf.s;
    }
  }
}

// ---------------------------------------------------------------------------
__global__ __launch_bounds__(256) void gemm_out(
    const short* __restrict__ A, const short* __restrict__ B,
    const float* __restrict__ bias, float* __restrict__ C) {
  __shared__ __align__(16) short As[128 * 32];
  __shared__ __align__(16) short Bs[128 * 32];
  const int t = threadIdx.x;
  const int wid = t >> 6, lane = t & 63, l15 = lane & 15, quad = lane >> 4;
  const int bm = blockIdx.x * 128, bn = blockIdx.y * 128;
  const int mq = (wid & 1) * 64, nq = (wid >> 1) * 64;
  const int srow = lane >> 2, scol = (lane & 3) * 8;

  f32x4 acc[4][4] = {};
  const short* gA0 = A + (size_t)(bm + wid * 16 + srow) * 768 + scol;
  const short* gA1 = A + (size_t)(bm + 64 + wid * 16 + srow) * 768 + scol;
  const short* gB0 = B + (size_t)(bn + wid * 16 + srow) * 768 + scol;
  const short* gB1 = B + (size_t)(bn + 64 + wid * 16 + srow) * 768 + scol;

  for (int k0 = 0; k0 < 768; k0 += 32) {
    GLL(gA0 + k0, &As[(wid * 16) * 32]);
    GLL(gA1 + k0, &As[(64 + wid * 16) * 32]);
    GLL(gB0 + k0, &Bs[(wid * 16) * 32]);
    GLL(gB1 + k0, &Bs[(64 + wid * 16) * 32]);
    __syncthreads();
    short8 a[4], b[4];
#pragma unroll
    for (int mt = 0; mt < 4; ++mt)
      a[mt] = *(const short8*)&As[(mq + mt * 16 + l15) * 32 + quad * 8];
#pragma unroll
    for (int nt = 0; nt < 4; ++nt)
      b[nt] = *(const short8*)&Bs[(nq + nt * 16 + l15) * 32 + quad * 8];
#pragma unroll
    for (int mt = 0; mt < 4; ++mt)
#pragma unroll
      for (int nt = 0; nt < 4; ++nt)
        acc[mt][nt] = MFMA(a[mt], b[nt], acc[mt][nt]);
    __syncthreads();
  }

#pragma unroll
  for (int mt = 0; mt < 4; ++mt)
#pragma unroll
    for (int nt = 0; nt < 4; ++nt) {
      int col = bn + nq + nt * 16 + l15;
      float bias_v = bias[col];
#pragma unroll
      for (int i = 0; i < 4; ++i) {
        int row = bm + mq + mt * 16 + quad * 4 + i;
        C[(size_t)row * 768 + col] = acc[mt][nt][i] + bias_v;
      }
    }
}

// ---------------------------------------------------------------------------
extern "C" void kernel_launch(void* const* d_in, const int* in_sizes, int n_in,
                              void* d_out, int out_size, void* d_ws,
                              size_t ws_size, hipStream_t stream) {
  const float* hs   = (const float*)d_in[0];
  const float* mask = (const float*)d_in[1];
  const float* Wq   = (const float*)d_in[2];
  const float* bq   = (const float*)d_in[3];
  const float* Wk   = (const float*)d_in[4];
  const float* bk   = (const float*)d_in[5];
  const float* Wv   = (const float*)d_in[6];
  const float* bv   = (const float*)d_in[7];
  const float* Wo   = (const float*)d_in[8];
  const float* bo   = (const float*)d_in[9];

  char* ws = (char*)d_ws;
  short* Xb    = (short*)(ws);               // 8192x768  bf16  12.58MB
  short* Wqkvb = (short*)(ws + 12582912);    // 2304x768  bf16   3.54MB
  short* Wob   = (short*)(ws + 16121856);    // 768x768   bf16   1.18MB
  short* Qb    = (short*)(ws + 17301504);    // 8192x768  bf16  12.58MB
  short* Kb    = (short*)(ws + 29884416);    // 8192x768  bf16  12.58MB
  short* Vtg   = (short*)(ws + 42467328);    // [4][12][64][2048] 12.58MB
  short* Ctxb  = (short*)(ws + 55050240);    // 8192x768  bf16  12.58MB
  float* mbias = (float*)(ws + 67633152);    // 8192 f32  32KB

  to_bf16<<<6144, 256, 0, stream>>>(hs, Xb, 1572864);
  conv_wqkv<<<1728, 256, 0, stream>>>(Wq, Wk, Wv, Wqkvb);
  to_bf16<<<576, 256, 0, stream>>>(Wo, Wob, 147456);
  maskbias<<<32, 256, 0, stream>>>(mask, mbias);

  gemm_qkv<<<dim3(64, 18), 256, 0, stream>>>(Xb, Wqkvb, bq, bk, bv,
                                             Qb, Kb, Vtg);
  attn_v7<<<dim3(48, 16), 256, 0, stream>>>(Qb, Kb, Vtg, mbias, Ctxb);
  gemm_out<<<dim3(64, 6), 256, 0, stream>>>(Ctxb, Wob, bo, (float*)d_out);
}

// Round 10
// 236.041 us; speedup vs baseline: 1.5167x; 1.0059x over previous
//
#include <hip/hip_runtime.h>
#include <hip/hip_bf16.h>

#define SEQ   2048
#define NH    12
#define MTOK  8192   // 4*2048 token rows

typedef __attribute__((ext_vector_type(8))) short short8;
typedef __attribute__((ext_vector_type(4))) short short4v;
typedef __attribute__((ext_vector_type(4))) float f32x4;

__device__ inline short f2bf(float x) {
  __hip_bfloat16 h = __float2bfloat16(x);
  return *(short*)&h;
}

#define GLL(gp, lp) __builtin_amdgcn_global_load_lds( \
    (const __attribute__((address_space(1))) void*)(gp), \
    (__attribute__((address_space(3))) void*)(lp), 16, 0, 0)

#define MFMA(a, b, c) __builtin_amdgcn_mfma_f32_16x16x32_bf16(a, b, c, 0, 0, 0)

// K=16 bf16 MFMA — device-pass hedge; host pass only parses, give it a stub
#if !defined(__HIP_DEVICE_COMPILE__)
#define MFMA16(a, b, c) (c)
#elif __has_builtin(__builtin_amdgcn_mfma_f32_16x16x16bf16_1k)
#define MFMA16(a, b, c) __builtin_amdgcn_mfma_f32_16x16x16bf16_1k(a, b, c, 0, 0, 0)
#elif __has_builtin(__builtin_amdgcn_mfma_f32_16x16x16_bf16)
#define MFMA16(a, b, c) __builtin_amdgcn_mfma_f32_16x16x16_bf16(a, b, c, 0, 0, 0)
#else
#error "no 16x16x16 bf16 mfma builtin on device"
#endif

// native exp2 (1 VALU op) hedge
#if !defined(__HIP_DEVICE_COMPILE__)
#define EXP2(x) (x)
#elif __has_builtin(__builtin_amdgcn_exp2f)
#define EXP2(x) __builtin_amdgcn_exp2f(x)
#else
#define EXP2(x) __expf((x) * 0.6931471805599453f)
#endif

// pack two fp32 -> bf16x2 dword (round-half-away; inputs finite)
__device__ inline unsigned pack2bf(float a, float b) {
  unsigned ua = __float_as_uint(a) + 0x8000u;
  unsigned ub = __float_as_uint(b) + 0x8000u;
#if defined(__HIP_DEVICE_COMPILE__) && __has_builtin(__builtin_amdgcn_perm)
  return __builtin_amdgcn_perm(ub, ua, 0x07060302u);
#else
  return (ub & 0xFFFF0000u) | (ua >> 16);
#endif
}

// build a short4v B-fragment from two packed dwords (named storage, no temp)
union PackFrag {
  unsigned u[2];
  short4v s;
};

// log2(e)*0.125 folded into Q so p = exp2(S + maskbias)
#define QSCALE 0.18033688011112042f
#define MBSCALE -14426.950408889634f  // -10000*log2(e)

// ---------------------------------------------------------------------------
__global__ __launch_bounds__(256) void to_bf16(
    const float* __restrict__ in, short* __restrict__ out, int n4) {
  int i = blockIdx.x * 256 + threadIdx.x;
  if (i >= n4) return;
  float4 v = ((const float4*)in)[i];
  short4v o;
  o[0] = f2bf(v.x); o[1] = f2bf(v.y); o[2] = f2bf(v.z); o[3] = f2bf(v.w);
  ((short4v*)out)[i] = o;
}

// fused Wq|Wk|Wv -> Wqkvb [2304][768] and Wo -> Wob [768][768]
__global__ __launch_bounds__(256) void conv_w(
    const float* __restrict__ Wq, const float* __restrict__ Wk,
    const float* __restrict__ Wv, const float* __restrict__ Wo,
    short* __restrict__ Wqkvb, short* __restrict__ Wob) {
  int idx = blockIdx.x * 256 + threadIdx.x;  // 3072*192
  int r = idx / 192, c = (idx - r * 192) * 4;
  const float* src;
  short* dst;
  int rr;
  if (r < 768)       { src = Wq; rr = r;        dst = Wqkvb; }
  else if (r < 1536) { src = Wk; rr = r - 768;  dst = Wqkvb; }
  else if (r < 2304) { src = Wv; rr = r - 1536; dst = Wqkvb; }
  else               { src = Wo; rr = r - 2304; dst = Wob; r = rr; }
  float4 v = *(const float4*)&src[(size_t)rr * 768 + c];
  short4v o;
  o[0] = f2bf(v.x); o[1] = f2bf(v.y); o[2] = f2bf(v.z); o[3] = f2bf(v.w);
  *(short4v*)&dst[(size_t)r * 768 + c] = o;
}

__global__ __launch_bounds__(256) void maskbias(
    const float* __restrict__ mask, float* __restrict__ mb) {
  int i = blockIdx.x * 256 + threadIdx.x;
  if (i < MTOK) mb[i] = (1.f - mask[i]) * MBSCALE;
}

// ---------------------------------------------------------------------------
// BK=64 GEMM core: 128x128 tile, 12 k-iterations for K=768, 32 MFMA/iter,
// XOR-chunk-swizzled LDS (physical chunk = logical ^ (row&7)) to avoid the
// 8-way conflict of 128B row stride; swizzle carried in GLL source address.
// ---------------------------------------------------------------------------
#define GEMM_BK64_LOOP(Aptr, Bptr)                                            \
  __shared__ __align__(16) short As[128 * 64];                                \
  __shared__ __align__(16) short Bs[128 * 64];                                \
  const int t = threadIdx.x;                                                  \
  const int wid = t >> 6, lane = t & 63, l15 = lane & 15, quad = lane >> 4;   \
  const int bm = blockIdx.x * 128, bn = blockIdx.y * 128;                     \
  const int mq = (wid & 1) * 64, nq = (wid >> 1) * 64;                        \
  const int srow8 = lane >> 3;   /* 0..7 row within 8-row GLL block */        \
  const int schunk = lane & 7;   /* physical 16B chunk */                     \
  const int scol = (schunk ^ srow8) * 8;  /* swizzled source col (shorts) */  \
  f32x4 acc[4][4] = {};                                                       \
  const short *gA[4], *gB[4];                                                 \
  _Pragma("unroll") for (int g = 0; g < 4; ++g) {                             \
    int row = wid * 32 + g * 8 + srow8;                                       \
    gA[g] = (Aptr) + (size_t)(bm + row) * 768 + scol;                         \
    gB[g] = (Bptr) + (size_t)(bn + row) * 768 + scol;                         \
  }                                                                           \
  for (int k0 = 0; k0 < 768; k0 += 64) {                                      \
    _Pragma("unroll") for (int g = 0; g < 4; ++g)                             \
      GLL(gA[g] + k0, &As[(wid * 32 + g * 8) * 64]);                          \
    _Pragma("unroll") for (int g = 0; g < 4; ++g)                             \
      GLL(gB[g] + k0, &Bs[(wid * 32 + g * 8) * 64]);                          \
    __syncthreads();                                                          \
    _Pragma("unroll") for (int ks = 0; ks < 2; ++ks) {                        \
      short8 a[4], b[4];                                                      \
      _Pragma("unroll") for (int mt = 0; mt < 4; ++mt)                        \
        a[mt] = *(const short8*)&As[(mq + mt * 16 + l15) * 64 +               \
                                    (((ks * 4 + quad) ^ (l15 & 7)) * 8)];     \
      _Pragma("unroll") for (int nt = 0; nt < 4; ++nt)                        \
        b[nt] = *(const short8*)&Bs[(nq + nt * 16 + l15) * 64 +               \
                                    (((ks * 4 + quad) ^ (l15 & 7)) * 8)];     \
      _Pragma("unroll") for (int mt = 0; mt < 4; ++mt)                        \
        _Pragma("unroll") for (int nt = 0; nt < 4; ++nt)                      \
          acc[mt][nt] = MFMA(a[mt], b[nt], acc[mt][nt]);                      \
    }                                                                         \
    __syncthreads();                                                          \
  }

// ---------------------------------------------------------------------------
// QKV GEMM: writes Qb (pre-scaled QSCALE), Kb, Vt (transposed [b,h,d,s]).
// ---------------------------------------------------------------------------
__global__ __launch_bounds__(256) void gemm_qkv(
    const short* __restrict__ A, const short* __restrict__ B,
    const float* __restrict__ bq, const float* __restrict__ bk,
    const float* __restrict__ bv, short* __restrict__ Qb,
    short* __restrict__ Kb, short* __restrict__ Vt) {
  GEMM_BK64_LOOP(A, B)

  const int seg = bn >= 1536 ? 2 : (bn >= 768 ? 1 : 0);
  const float* bias = seg == 0 ? bq : (seg == 1 ? bk : bv);
  const int colbase = bn - seg * 768;

  if (seg < 2) {
    short* dst = seg == 0 ? Qb : Kb;
    const float sc = seg == 0 ? QSCALE : 1.f;
#pragma unroll
    for (int mt = 0; mt < 4; ++mt)
#pragma unroll
      for (int nt = 0; nt < 4; ++nt) {
        int col = colbase + nq + nt * 16 + l15;
        float bias_v = bias[col];
#pragma unroll
        for (int i = 0; i < 4; ++i) {
          int row = bm + mq + mt * 16 + quad * 4 + i;
          dst[(size_t)row * 768 + col] = f2bf((acc[mt][nt][i] + bias_v) * sc);
        }
      }
  } else {
#pragma unroll
    for (int mt = 0; mt < 4; ++mt) {
      int row0 = bm + mq + mt * 16 + quad * 4;
      int b_ = row0 >> 11, s = row0 & 2047;
#pragma unroll
      for (int nt = 0; nt < 4; ++nt) {
        int col = colbase + nq + nt * 16 + l15;
        float bias_v = bias[col];
        int h = col >> 6, d = col & 63;
        short4v pv;
#pragma unroll
        for (int i = 0; i < 4; ++i) pv[i] = f2bf(acc[mt][nt][i] + bias_v);
        *(short4v*)&Vt[(((size_t)b_ * NH + h) * 64 + d) * 2048 + s] = pv;
      }
    }
  }
}

// ---------------------------------------------------------------------------
// Output GEMM: out[8192,768] = Ctx @ Wo^T + bo, fp32 out.
// ---------------------------------------------------------------------------
__global__ __launch_bounds__(256) void gemm_out(
    const short* __restrict__ A, const short* __restrict__ B,
    const float* __restrict__ bias, float* __restrict__ C) {
  GEMM_BK64_LOOP(A, B)

#pragma unroll
  for (int mt = 0; mt < 4; ++mt)
#pragma unroll
    for (int nt = 0; nt < 4; ++nt) {
      int col = bn + nq + nt * 16 + l15;
      float bias_v = bias[col];
#pragma unroll
      for (int i = 0; i < 4; ++i) {
        int row = bm + mq + mt * 16 + quad * 4 + i;
        C[(size_t)row * 768 + col] = acc[mt][nt][i] + bias_v;
      }
    }
}

// ---------------------------------------------------------------------------
// attn_v7 (unchanged from r9): S-transposed register-resident-P flash attn.
// S^T = K.Q^T; S^T C-layout == B-operand layout of 16x16x16 MFMA -> P feeds
// PV directly from registers. l via ones-MFMA. LDS 16KB, XOR-chunk swizzle.
// ---------------------------------------------------------------------------
__global__ __launch_bounds__(256, 3) void attn_v7(
    const short* __restrict__ Qb, const short* __restrict__ Kb,
    const short* __restrict__ Vt, const float* __restrict__ maskb,
    short* __restrict__ Ctx) {
  __shared__ __align__(16) short Ks[64 * 64];   // [key][dchunk^swz]
  __shared__ __align__(16) short Vs[64 * 64];   // [d][keychunk^swz]
  const int t = threadIdx.x;
  const int w = t >> 6, lane = t & 63, l15 = lane & 15, quad = lane >> 4;
  const int bh = blockIdx.x, b = bh / NH, h = bh % NH;
  const int q0 = blockIdx.y * 128;

  short8 qa[2][2];
#pragma unroll
  for (int qt = 0; qt < 2; ++qt)
#pragma unroll
    for (int ks = 0; ks < 2; ++ks) {
      int row = b * 2048 + q0 + w * 32 + qt * 16 + l15;
      qa[qt][ks] = *(const short8*)&Qb[(size_t)row * 768 + h * 64 + ks * 32 + quad * 8];
    }

  f32x4 O[2][4] = {};     // O^T tiles: [qt][dt], D[m=d][n=q]
  f32x4 lacc[2] = {};     // l[q] replicated across rows
  short4v ones4;
#pragma unroll
  for (int j = 0; j < 4; ++j) ones4[j] = (short)0x3F80;  // bf16 1.0

  const int r0 = w * 16 + (lane >> 3);
  const int pc = lane & 7;
  const int swz0 = (pc ^ (r0 & 7)) * 8;
  const int swz1 = (pc ^ ((r0 + 8) & 7)) * 8;
  const short* gK0 = Kb + (size_t)(b * 2048 + r0) * 768 + h * 64 + swz0;
  const short* gK1 = Kb + (size_t)(b * 2048 + r0 + 8) * 768 + h * 64 + swz1;
  const short* gV0 = Vt + ((size_t)bh * 64 + r0) * 2048 + swz0;
  const short* gV1 = Vt + ((size_t)bh * 64 + r0 + 8) * 2048 + swz1;
  const float* mb = maskb + b * 2048;
  const int rs = l15 & 7;  // read-side swizzle key

  for (int k0 = 0; k0 < SEQ; k0 += 64) {
    GLL(gK0 + (size_t)k0 * 768, &Ks[(w * 16) * 64]);
    GLL(gK1 + (size_t)k0 * 768, &Ks[(w * 16 + 8) * 64]);
    GLL(gV0 + k0, &Vs[(w * 16) * 64]);
    GLL(gV1 + k0, &Vs[(w * 16 + 8) * 64]);
    __syncthreads();

    // S^T[kt][qt] = K.Q^T   (rows=key, cols=q)
    f32x4 S[4][2] = {};
#pragma unroll
    for (int ks = 0; ks < 2; ++ks) {
      short8 kb[4];
#pragma unroll
      for (int kt = 0; kt < 4; ++kt)
        kb[kt] = *(const short8*)&Ks[(kt * 16 + l15) * 64 +
                                     (((ks * 4 + quad) ^ rs) * 8)];
#pragma unroll
      for (int kt = 0; kt < 4; ++kt) {
        S[kt][0] = MFMA(kb[kt], qa[0][ks], S[kt][0]);
        S[kt][1] = MFMA(kb[kt], qa[1][ks], S[kt][1]);
      }
    }

    // p = exp2(S^T + maskbias[key]) -> packed bf16 B-fragments (registers)
    short4v pb[4][2];
#pragma unroll
    for (int kt = 0; kt < 4; ++kt) {
      float4 mb4 = *(const float4*)&mb[k0 + kt * 16 + quad * 4];
#pragma unroll
      for (int qt = 0; qt < 2; ++qt) {
        float p0 = EXP2(S[kt][qt][0] + mb4.x);
        float p1 = EXP2(S[kt][qt][1] + mb4.y);
        float p2 = EXP2(S[kt][qt][2] + mb4.z);
        float p3 = EXP2(S[kt][qt][3] + mb4.w);
        PackFrag pf;
        pf.u[0] = pack2bf(p0, p1);
        pf.u[1] = pack2bf(p2, p3);
        pb[kt][qt] = pf.s;
      }
    }

    // l += P.1 (per-lane l[q] in all rows)
#pragma unroll
    for (int kt = 0; kt < 4; ++kt) {
      lacc[0] = MFMA16(ones4, pb[kt][0], lacc[0]);
      lacc[1] = MFMA16(ones4, pb[kt][1], lacc[1]);
    }

    // O^T += V^T.P^T : A = V^T[d][key-chunk] (ds_read_b64), B = pb
#pragma unroll
    for (int kt = 0; kt < 4; ++kt) {
#pragma unroll
      for (int dt = 0; dt < 4; ++dt) {
        short4v av = *(const short4v*)&Vs[(dt * 16 + l15) * 64 +
            (((kt * 2 + (quad >> 1)) ^ rs) * 8) + (quad & 1) * 4];
        O[0][dt] = MFMA16(av, pb[kt][0], O[0][dt]);
        O[1][dt] = MFMA16(av, pb[kt][1], O[1][dt]);
      }
    }
    __syncthreads();
  }

  // epilogue: lane holds O^T[d=quad*4+i][q=l15]; l[q] = lacc[qt][any]
#pragma unroll
  for (int qt = 0; qt < 2; ++qt) {
    float inv = 1.f / lacc[qt][0];
    int row = b * 2048 + q0 + w * 32 + qt * 16 + l15;
#pragma unroll
    for (int dt = 0; dt < 4; ++dt) {
      PackFrag pf;
      pf.u[0] = pack2bf(O[qt][dt][0] * inv, O[qt][dt][1] * inv);
      pf.u[1] = pack2bf(O[qt][dt][2] * inv, O[qt][dt][3] * inv);
      *(short4v*)&Ctx[(size_t)row * 768 + h * 64 + dt * 16 + quad * 4] = pf.s;
    }
  }
}

// ---------------------------------------------------------------------------
extern "C" void kernel_launch(void* const* d_in, const int* in_sizes, int n_in,
                              void* d_out, int out_size, void* d_ws,
                              size_t ws_size, hipStream_t stream) {
  const float* hs   = (const float*)d_in[0];
  const float* mask = (const float*)d_in[1];
  const float* Wq   = (const float*)d_in[2];
  const float* bq   = (const float*)d_in[3];
  const float* Wk   = (const float*)d_in[4];
  const float* bk   = (const float*)d_in[5];
  const float* Wv   = (const float*)d_in[6];
  const float* bv   = (const float*)d_in[7];
  const float* Wo   = (const float*)d_in[8];
  const float* bo   = (const float*)d_in[9];

  char* ws = (char*)d_ws;
  short* Xb    = (short*)(ws);               // 8192x768  bf16  12.58MB
  short* Wqkvb = (short*)(ws + 12582912);    // 2304x768  bf16   3.54MB
  short* Wob   = (short*)(ws + 16121856);    // 768x768   bf16   1.18MB
  short* Qb    = (short*)(ws + 17301504);    // 8192x768  bf16  12.58MB
  short* Kb    = (short*)(ws + 29884416);    // 8192x768  bf16  12.58MB
  short* Vtg   = (short*)(ws + 42467328);    // [4][12][64][2048] 12.58MB
  short* Ctxb  = (short*)(ws + 55050240);    // 8192x768  bf16  12.58MB
  float* mbias = (float*)(ws + 67633152);    // 8192 f32  32KB

  to_bf16<<<6144, 256, 0, stream>>>(hs, Xb, 1572864);
  conv_w<<<2304, 256, 0, stream>>>(Wq, Wk, Wv, Wo, Wqkvb, Wob);
  maskbias<<<32, 256, 0, stream>>>(mask, mbias);

  gemm_qkv<<<dim3(64, 18), 256, 0, stream>>>(Xb, Wqkvb, bq, bk, bv,
                                             Qb, Kb, Vtg);
  attn_v7<<<dim3(48, 16), 256, 0, stream>>>(Qb, Kb, Vtg, mbias, Ctxb);
  gemm_out<<<dim3(64, 6), 256, 0, stream>>>(Ctxb, Wob, bo, (float*)d_out);
}

// Round 11
// 229.114 us; speedup vs baseline: 1.5625x; 1.0302x over previous
//
#include <hip/hip_runtime.h>
#include <hip/hip_bf16.h>

#define SEQ   2048
#define NH    12
#define MTOK  8192   // 4*2048 token rows

typedef __attribute__((ext_vector_type(8))) short short8;
typedef __attribute__((ext_vector_type(4))) short short4v;
typedef __attribute__((ext_vector_type(4))) float f32x4;

__device__ inline short f2bf(float x) {
  __hip_bfloat16 h = __float2bfloat16(x);
  return *(short*)&h;
}

#define GLL(gp, lp) __builtin_amdgcn_global_load_lds( \
    (const __attribute__((address_space(1))) void*)(gp), \
    (__attribute__((address_space(3))) void*)(lp), 16, 0, 0)

#define MFMA(a, b, c) __builtin_amdgcn_mfma_f32_16x16x32_bf16(a, b, c, 0, 0, 0)

// K=16 bf16 MFMA — device-pass hedge; host pass only parses, give it a stub
#if !defined(__HIP_DEVICE_COMPILE__)
#define MFMA16(a, b, c) (c)
#elif __has_builtin(__builtin_amdgcn_mfma_f32_16x16x16bf16_1k)
#define MFMA16(a, b, c) __builtin_amdgcn_mfma_f32_16x16x16bf16_1k(a, b, c, 0, 0, 0)
#elif __has_builtin(__builtin_amdgcn_mfma_f32_16x16x16_bf16)
#define MFMA16(a, b, c) __builtin_amdgcn_mfma_f32_16x16x16_bf16(a, b, c, 0, 0, 0)
#else
#error "no 16x16x16 bf16 mfma builtin on device"
#endif

// native exp2 (1 VALU op) hedge
#if !defined(__HIP_DEVICE_COMPILE__)
#define EXP2(x) (x)
#elif __has_builtin(__builtin_amdgcn_exp2f)
#define EXP2(x) __builtin_amdgcn_exp2f(x)
#else
#define EXP2(x) __expf((x) * 0.6931471805599453f)
#endif

// pack two fp32 -> bf16x2 dword (round-half-away; inputs finite)
__device__ inline unsigned pack2bf(float a, float b) {
  unsigned ua = __float_as_uint(a) + 0x8000u;
  unsigned ub = __float_as_uint(b) + 0x8000u;
#if defined(__HIP_DEVICE_COMPILE__) && __has_builtin(__builtin_amdgcn_perm)
  return __builtin_amdgcn_perm(ub, ua, 0x07060302u);
#else
  return (ub & 0xFFFF0000u) | (ua >> 16);
#endif
}

union PackFrag {
  unsigned u[2];
  short4v s;
};

// log2(e)*0.125 folded into Q so p = exp2(S + maskbias)
#define QSCALE 0.18033688011112042f
#define MBSCALE -14426.950408889634f  // -10000*log2(e)

// ---------------------------------------------------------------------------
// Fused prep: hs->Xb bf16 | Wq|Wk|Wv->Wqkvb, Wo->Wob | mask->mbias
// ---------------------------------------------------------------------------
__global__ __launch_bounds__(256) void prep(
    const float* __restrict__ hs, const float* __restrict__ Wq,
    const float* __restrict__ Wk, const float* __restrict__ Wv,
    const float* __restrict__ Wo, const float* __restrict__ mask,
    short* __restrict__ Xb, short* __restrict__ Wqkvb,
    short* __restrict__ Wob, float* __restrict__ mbias) {
  int bid = blockIdx.x;
  if (bid < 6144) {
    int i = bid * 256 + threadIdx.x;     // 8192*192 float4s
    float4 v = ((const float4*)hs)[i];
    short4v o;
    o[0] = f2bf(v.x); o[1] = f2bf(v.y); o[2] = f2bf(v.z); o[3] = f2bf(v.w);
    ((short4v*)Xb)[i] = o;
  } else if (bid < 6144 + 2304) {
    int idx = (bid - 6144) * 256 + threadIdx.x;  // 3072*192
    int r = idx / 192, c = (idx - r * 192) * 4;
    const float* src;
    short* dst;
    int rr;
    if (r < 768)       { src = Wq; rr = r;        dst = Wqkvb; }
    else if (r < 1536) { src = Wk; rr = r - 768;  dst = Wqkvb; }
    else if (r < 2304) { src = Wv; rr = r - 1536; dst = Wqkvb; }
    else               { src = Wo; rr = r - 2304; dst = Wob; r = rr; }
    float4 v = *(const float4*)&src[(size_t)rr * 768 + c];
    short4v o;
    o[0] = f2bf(v.x); o[1] = f2bf(v.y); o[2] = f2bf(v.z); o[3] = f2bf(v.w);
    *(short4v*)&dst[(size_t)r * 768 + c] = o;
  } else {
    int i = (bid - 6144 - 2304) * 256 + threadIdx.x;
    if (i < MTOK) mbias[i] = (1.f - mask[i]) * MBSCALE;
  }
}

// ---------------------------------------------------------------------------
// BK=64 GEMM core (r10, unchanged): 128x128 tile, XOR-chunk-swizzled LDS.
// ---------------------------------------------------------------------------
#define GEMM_BK64_LOOP(Aptr, Bptr)                                            \
  __shared__ __align__(16) short As[128 * 64];                                \
  __shared__ __align__(16) short Bs[128 * 64];                                \
  const int t = threadIdx.x;                                                  \
  const int wid = t >> 6, lane = t & 63, l15 = lane & 15, quad = lane >> 4;   \
  const int bm = blockIdx.x * 128, bn = blockIdx.y * 128;                     \
  const int mq = (wid & 1) * 64, nq = (wid >> 1) * 64;                        \
  const int srow8 = lane >> 3;                                                \
  const int schunk = lane & 7;                                                \
  const int scol = (schunk ^ srow8) * 8;                                      \
  f32x4 acc[4][4] = {};                                                       \
  const short *gA[4], *gB[4];                                                 \
  _Pragma("unroll") for (int g = 0; g < 4; ++g) {                             \
    int row = wid * 32 + g * 8 + srow8;                                       \
    gA[g] = (Aptr) + (size_t)(bm + row) * 768 + scol;                         \
    gB[g] = (Bptr) + (size_t)(bn + row) * 768 + scol;                         \
  }                                                                           \
  for (int k0 = 0; k0 < 768; k0 += 64) {                                      \
    _Pragma("unroll") for (int g = 0; g < 4; ++g)                             \
      GLL(gA[g] + k0, &As[(wid * 32 + g * 8) * 64]);                          \
    _Pragma("unroll") for (int g = 0; g < 4; ++g)                             \
      GLL(gB[g] + k0, &Bs[(wid * 32 + g * 8) * 64]);                          \
    __syncthreads();                                                          \
    _Pragma("unroll") for (int ks = 0; ks < 2; ++ks) {                        \
      short8 a[4], b[4];                                                      \
      _Pragma("unroll") for (int mt = 0; mt < 4; ++mt)                        \
        a[mt] = *(const short8*)&As[(mq + mt * 16 + l15) * 64 +               \
                                    (((ks * 4 + quad) ^ (l15 & 7)) * 8)];     \
      _Pragma("unroll") for (int nt = 0; nt < 4; ++nt)                        \
        b[nt] = *(const short8*)&Bs[(nq + nt * 16 + l15) * 64 +               \
                                    (((ks * 4 + quad) ^ (l15 & 7)) * 8)];     \
      _Pragma("unroll") for (int mt = 0; mt < 4; ++mt)                        \
        _Pragma("unroll") for (int nt = 0; nt < 4; ++nt)                      \
          acc[mt][nt] = MFMA(a[mt], b[nt], acc[mt][nt]);                      \
    }                                                                         \
    __syncthreads();                                                          \
  }

// ---------------------------------------------------------------------------
__global__ __launch_bounds__(256) void gemm_qkv(
    const short* __restrict__ A, const short* __restrict__ B,
    const float* __restrict__ bq, const float* __restrict__ bk,
    const float* __restrict__ bv, short* __restrict__ Qb,
    short* __restrict__ Kb, short* __restrict__ Vt) {
  GEMM_BK64_LOOP(A, B)

  const int seg = bn >= 1536 ? 2 : (bn >= 768 ? 1 : 0);
  const float* bias = seg == 0 ? bq : (seg == 1 ? bk : bv);
  const int colbase = bn - seg * 768;

  if (seg < 2) {
    short* dst = seg == 0 ? Qb : Kb;
    const float sc = seg == 0 ? QSCALE : 1.f;
#pragma unroll
    for (int mt = 0; mt < 4; ++mt)
#pragma unroll
      for (int nt = 0; nt < 4; ++nt) {
        int col = colbase + nq + nt * 16 + l15;
        float bias_v = bias[col];
#pragma unroll
        for (int i = 0; i < 4; ++i) {
          int row = bm + mq + mt * 16 + quad * 4 + i;
          dst[(size_t)row * 768 + col] = f2bf((acc[mt][nt][i] + bias_v) * sc);
        }
      }
  } else {
#pragma unroll
    for (int mt = 0; mt < 4; ++mt) {
      int row0 = bm + mq + mt * 16 + quad * 4;
      int b_ = row0 >> 11, s = row0 & 2047;
#pragma unroll
      for (int nt = 0; nt < 4; ++nt) {
        int col = colbase + nq + nt * 16 + l15;
        float bias_v = bias[col];
        int h = col >> 6, d = col & 63;
        short4v pv;
#pragma unroll
        for (int i = 0; i < 4; ++i) pv[i] = f2bf(acc[mt][nt][i] + bias_v);
        *(short4v*)&Vt[(((size_t)b_ * NH + h) * 64 + d) * 2048 + s] = pv;
      }
    }
  }
}

// ---------------------------------------------------------------------------
__global__ __launch_bounds__(256) void gemm_out(
    const short* __restrict__ A, const short* __restrict__ B,
    const float* __restrict__ bias, float* __restrict__ C) {
  GEMM_BK64_LOOP(A, B)

#pragma unroll
  for (int mt = 0; mt < 4; ++mt)
#pragma unroll
    for (int nt = 0; nt < 4; ++nt) {
      int col = bn + nq + nt * 16 + l15;
      float bias_v = bias[col];
#pragma unroll
      for (int i = 0; i < 4; ++i) {
        int row = bm + mq + mt * 16 + quad * 4 + i;
        C[(size_t)row * 768 + col] = acc[mt][nt][i] + bias_v;
      }
    }
}

// ---------------------------------------------------------------------------
// attn_v8: r9's register-resident-P flash attention + LDS DOUBLE BUFFER.
// Pipeline per tile: barrier (drains prefetch issued a full compute phase
// ago -> ~free) ; issue GLL for tile t+1 into other buffer ; compute tile t.
// One barrier/tile, drain hidden behind compute. LDS 32KB (2x Ks+Vs).
// ---------------------------------------------------------------------------
__global__ __launch_bounds__(256, 3) void attn_v8(
    const short* __restrict__ Qb, const short* __restrict__ Kb,
    const short* __restrict__ Vt, const float* __restrict__ maskb,
    short* __restrict__ Ctx) {
  __shared__ __align__(16) short Ks[2][64 * 64];   // [buf][key][dchunk^swz]
  __shared__ __align__(16) short Vs[2][64 * 64];   // [buf][d][keychunk^swz]
  const int t = threadIdx.x;
  const int w = t >> 6, lane = t & 63, l15 = lane & 15, quad = lane >> 4;
  const int bh = blockIdx.x, b = bh / NH, h = bh % NH;
  const int q0 = blockIdx.y * 128;

  short8 qa[2][2];
#pragma unroll
  for (int qt = 0; qt < 2; ++qt)
#pragma unroll
    for (int ks = 0; ks < 2; ++ks) {
      int row = b * 2048 + q0 + w * 32 + qt * 16 + l15;
      qa[qt][ks] = *(const short8*)&Qb[(size_t)row * 768 + h * 64 + ks * 32 + quad * 8];
    }

  f32x4 O[2][4] = {};     // O^T tiles: [qt][dt], D[m=d][n=q]
  f32x4 lacc[2] = {};     // l[q] replicated across rows
  short4v ones4;
#pragma unroll
  for (int j = 0; j < 4; ++j) ones4[j] = (short)0x3F80;  // bf16 1.0

  const int r0 = w * 16 + (lane >> 3);
  const int pc = lane & 7;
  const int swz0 = (pc ^ (r0 & 7)) * 8;
  const int swz1 = (pc ^ ((r0 + 8) & 7)) * 8;
  const short* gK0 = Kb + (size_t)(b * 2048 + r0) * 768 + h * 64 + swz0;
  const short* gK1 = Kb + (size_t)(b * 2048 + r0 + 8) * 768 + h * 64 + swz1;
  const short* gV0 = Vt + ((size_t)bh * 64 + r0) * 2048 + swz0;
  const short* gV1 = Vt + ((size_t)bh * 64 + r0 + 8) * 2048 + swz1;
  const float* mb = maskb + b * 2048;
  const int rs = l15 & 7;  // read-side swizzle key

  // prologue: tile 0 -> buffer 0
  GLL(gK0, &Ks[0][(w * 16) * 64]);
  GLL(gK1, &Ks[0][(w * 16 + 8) * 64]);
  GLL(gV0, &Vs[0][(w * 16) * 64]);
  GLL(gV1, &Vs[0][(w * 16 + 8) * 64]);

  for (int ti = 0; ti < 32; ++ti) {
    const int cur = ti & 1;
    const int k0 = ti * 64;
    __syncthreads();  // drains tile-ti GLLs (in flight since last compute)

    // prefetch tile ti+1 into the other buffer (wraps on last iter; harmless)
    {
      const size_t kn = (size_t)(((ti + 1) & 31) * 64);
      GLL(gK0 + kn * 768, &Ks[1 - cur][(w * 16) * 64]);
      GLL(gK1 + kn * 768, &Ks[1 - cur][(w * 16 + 8) * 64]);
      GLL(gV0 + kn, &Vs[1 - cur][(w * 16) * 64]);
      GLL(gV1 + kn, &Vs[1 - cur][(w * 16 + 8) * 64]);
    }

    // S^T[kt][qt] = K.Q^T   (rows=key, cols=q)
    f32x4 S[4][2] = {};
#pragma unroll
    for (int ks = 0; ks < 2; ++ks) {
      short8 kb[4];
#pragma unroll
      for (int kt = 0; kt < 4; ++kt)
        kb[kt] = *(const short8*)&Ks[cur][(kt * 16 + l15) * 64 +
                                         (((ks * 4 + quad) ^ rs) * 8)];
#pragma unroll
      for (int kt = 0; kt < 4; ++kt) {
        S[kt][0] = MFMA(kb[kt], qa[0][ks], S[kt][0]);
        S[kt][1] = MFMA(kb[kt], qa[1][ks], S[kt][1]);
      }
    }

    // p = exp2(S^T + maskbias[key]) -> packed bf16 B-fragments (registers)
    short4v pb[4][2];
#pragma unroll
    for (int kt = 0; kt < 4; ++kt) {
      float4 mb4 = *(const float4*)&mb[k0 + kt * 16 + quad * 4];
#pragma unroll
      for (int qt = 0; qt < 2; ++qt) {
        float p0 = EXP2(S[kt][qt][0] + mb4.x);
        float p1 = EXP2(S[kt][qt][1] + mb4.y);
        float p2 = EXP2(S[kt][qt][2] + mb4.z);
        float p3 = EXP2(S[kt][qt][3] + mb4.w);
        PackFrag pf;
        pf.u[0] = pack2bf(p0, p1);
        pf.u[1] = pack2bf(p2, p3);
        pb[kt][qt] = pf.s;
      }
    }

    // l += P.1
#pragma unroll
    for (int kt = 0; kt < 4; ++kt) {
      lacc[0] = MFMA16(ones4, pb[kt][0], lacc[0]);
      lacc[1] = MFMA16(ones4, pb[kt][1], lacc[1]);
    }

    // O^T += V^T.P^T
#pragma unroll
    for (int kt = 0; kt < 4; ++kt) {
#pragma unroll
      for (int dt = 0; dt < 4; ++dt) {
        short4v av = *(const short4v*)&Vs[cur][(dt * 16 + l15) * 64 +
            (((kt * 2 + (quad >> 1)) ^ rs) * 8) + (quad & 1) * 4];
        O[0][dt] = MFMA16(av, pb[kt][0], O[0][dt]);
        O[1][dt] = MFMA16(av, pb[kt][1], O[1][dt]);
      }
    }
  }

  // epilogue: lane holds O^T[d=quad*4+i][q=l15]; l[q] = lacc[qt][any]
#pragma unroll
  for (int qt = 0; qt < 2; ++qt) {
    float inv = 1.f / lacc[qt][0];
    int row = b * 2048 + q0 + w * 32 + qt * 16 + l15;
#pragma unroll
    for (int dt = 0; dt < 4; ++dt) {
      PackFrag pf;
      pf.u[0] = pack2bf(O[qt][dt][0] * inv, O[qt][dt][1] * inv);
      pf.u[1] = pack2bf(O[qt][dt][2] * inv, O[qt][dt][3] * inv);
      *(short4v*)&Ctx[(size_t)row * 768 + h * 64 + dt * 16 + quad * 4] = pf.s;
    }
  }
}

// ---------------------------------------------------------------------------
extern "C" void kernel_launch(void* const* d_in, const int* in_sizes, int n_in,
                              void* d_out, int out_size, void* d_ws,
                              size_t ws_size, hipStream_t stream) {
  const float* hs   = (const float*)d_in[0];
  const float* mask = (const float*)d_in[1];
  const float* Wq   = (const float*)d_in[2];
  const float* bq   = (const float*)d_in[3];
  const float* Wk   = (const float*)d_in[4];
  const float* bk   = (const float*)d_in[5];
  const float* Wv   = (const float*)d_in[6];
  const float* bv   = (const float*)d_in[7];
  const float* Wo   = (const float*)d_in[8];
  const float* bo   = (const float*)d_in[9];

  char* ws = (char*)d_ws;
  short* Xb    = (short*)(ws);               // 8192x768  bf16  12.58MB
  short* Wqkvb = (short*)(ws + 12582912);    // 2304x768  bf16   3.54MB
  short* Wob   = (short*)(ws + 16121856);    // 768x768   bf16   1.18MB
  short* Qb    = (short*)(ws + 17301504);    // 8192x768  bf16  12.58MB
  short* Kb    = (short*)(ws + 29884416);    // 8192x768  bf16  12.58MB
  short* Vtg   = (short*)(ws + 42467328);    // [4][12][64][2048] 12.58MB
  short* Ctxb  = (short*)(ws + 55050240);    // 8192x768  bf16  12.58MB
  float* mbias = (float*)(ws + 67633152);    // 8192 f32  32KB

  prep<<<8480, 256, 0, stream>>>(hs, Wq, Wk, Wv, Wo, mask,
                                 Xb, Wqkvb, Wob, mbias);
  gemm_qkv<<<dim3(64, 18), 256, 0, stream>>>(Xb, Wqkvb, bq, bk, bv,
                                             Qb, Kb, Vtg);
  attn_v8<<<dim3(48, 16), 256, 0, stream>>>(Qb, Kb, Vtg, mbias, Ctxb);
  gemm_out<<<dim3(64, 6), 256, 0, stream>>>(Ctxb, Wob, bo, (float*)d_out);
}